// Round 1
// baseline (12886.565 us; speedup 1.0000x reference)
//
#include <hip/hip_runtime.h>
#include <hip/hip_fp16.h>

// Problem constants
#define B_    64
#define NC_   512
#define T_    1024
#define SX_   32
#define F_    192
#define KTOT  1216      // 192 (x) + 512 (prev2) + 512 (h)
#define G4    2048      // 4*NC

typedef __attribute__((ext_vector_type(8))) _Float16 half8;
typedef __attribute__((ext_vector_type(4))) float f32x4;

// ws layout (bytes)
#define OFF_BIAS 4980736                   // after W16: 2048*1216*2
#define OFF_C    (OFF_BIAS + 2048*4)       // c-state: 64*512 f32
#define OFF_RING (OFF_C + B_*NC_*4)        // h ring: 64 slots * 64 * 512 f16
// total = OFF_RING + 64*64*512*2 = 9,314,304 bytes

__global__ __launch_bounds__(256) void prep_kernel(const float* __restrict__ Wih,
                                                   const float* __restrict__ Whh,
                                                   const float* __restrict__ bih,
                                                   const float* __restrict__ bhh,
                                                   _Float16* __restrict__ W16,
                                                   float* __restrict__ bias) {
    const int j = blockIdx.x;   // gate row 0..2047
    for (int k = threadIdx.x; k < KTOT; k += 256) {
        float v = (k < 704) ? Wih[j * 704 + k] : Whh[j * 512 + (k - 704)];
        W16[j * KTOT + k] = (_Float16)v;
    }
    if (threadIdx.x == 0) bias[j] = bih[j] + bhh[j];
}

#define KC   64
#define NKC  19      // 1216 / 64; region boundaries 192 and 704 are chunk-aligned
#define LDH  72      // padded LDS row stride in halfs (144 B: 16B-aligned, 2-way banks)

static constexpr int SMEM_AB = 2 * 64 * LDH * 2;   // 18432 B
static constexpr int SMEM_C  = 64 * 65 * 4;        // 16640 B

__global__ __launch_bounds__(512) void lstm_step(int t,
        const float* __restrict__ x,
        const _Float16* __restrict__ W16,
        const float* __restrict__ bias,
        float* __restrict__ c_st,
        _Float16* __restrict__ ring,
        float* __restrict__ out) {
    __shared__ __align__(16) unsigned char smem[(SMEM_AB > SMEM_C) ? SMEM_AB : SMEM_C];
    _Float16* Asm = (_Float16*)smem;
    _Float16* Bsm = (_Float16*)(smem + 64 * LDH * 2);
    float*    Csm = (float*)smem;

    const int tid  = threadIdx.x;
    const int lane = tid & 63;
    const int w    = tid >> 6;     // wave 0..7
    const int mh   = w >> 2;       // batch half (0..1)
    const int cq   = w & 3;        // 16-col quarter = gate type for this wave
    const int h0   = blockIdx.x * 16;   // 32 blocks cover 512 h-channels

    const int y  = t >> 5;
    const int xc = t & 31;

    // staging role: each thread stages one 16B chunk of A and of B per K-chunk
    const int sb  = tid >> 3;          // 0..63: A batch row / B gate row
    const int skk = (tid & 7) * 8;     // 0..56: k offset within chunk

    f32x4 acc0 = {0.f, 0.f, 0.f, 0.f};
    f32x4 acc1 = {0.f, 0.f, 0.f, 0.f};

    auto loadA = [&](int k0) -> half8 {
        half8 r = {0, 0, 0, 0, 0, 0, 0, 0};
        const int k = k0 + skk;
        if (k0 < F_) {
            // x gather: f = k, f = c*64 + py*8 + px, 8 consecutive px
            const int f  = k;
            const int c  = f >> 6;
            const int py = (f >> 3) & 7;
            const float* xs = x + (size_t)(((sb * 3 + c) * 256 + y * 8 + py)) * 256 + xc * 8;
            float4 v0 = *(const float4*)(xs);
            float4 v1 = *(const float4*)(xs + 4);
            r[0] = (_Float16)v0.x; r[1] = (_Float16)v0.y;
            r[2] = (_Float16)v0.z; r[3] = (_Float16)v0.w;
            r[4] = (_Float16)v1.x; r[5] = (_Float16)v1.y;
            r[6] = (_Float16)v1.z; r[7] = (_Float16)v1.w;
        } else if (k0 < 704) {
            if (t >= SX_) {   // prev2 = h(t-32); zeros for t < 32
                const int slot = (t - SX_) & 63;
                r = *(const half8*)(ring + ((size_t)slot * B_ + sb) * NC_ + (k - F_));
            }
        } else {
            if (t > 0) {      // h(t-1); zeros at t == 0
                const int slot = (t - 1) & 63;
                r = *(const half8*)(ring + ((size_t)slot * B_ + sb) * NC_ + (k - 704));
            }
        }
        return r;
    };
    auto loadB = [&](int k0) -> half8 {
        const int g  = sb >> 4;          // gate type 0..3
        const int hl = sb & 15;          // h within block slice
        const int j  = g * NC_ + h0 + hl;
        return *(const half8*)(W16 + (size_t)j * KTOT + k0 + skk);
    };

    half8 ra = loadA(0);
    half8 rb = loadB(0);

    for (int kc = 0; kc < NKC; ++kc) {
        __syncthreads();                       // LDS free (previous MFMA done)
        *(half8*)(Asm + sb * LDH + skk) = ra;
        *(half8*)(Bsm + sb * LDH + skk) = rb;
        __syncthreads();
        if (kc + 1 < NKC) {                    // prefetch next chunk under MFMA
            ra = loadA((kc + 1) * KC);
            rb = loadB((kc + 1) * KC);
        }
#pragma unroll
        for (int ks = 0; ks < 2; ++ks) {
            const int kof = ks * 32 + (lane >> 4) * 8;
            half8 bfrag  = *(const half8*)(Bsm + (cq * 16 + (lane & 15)) * LDH + kof);
            half8 afrag0 = *(const half8*)(Asm + (mh * 32 + (lane & 15)) * LDH + kof);
            half8 afrag1 = *(const half8*)(Asm + (mh * 32 + 16 + (lane & 15)) * LDH + kof);
            acc0 = __builtin_amdgcn_mfma_f32_16x16x32_f16(afrag0, bfrag, acc0, 0, 0, 0);
            acc1 = __builtin_amdgcn_mfma_f32_16x16x32_f16(afrag1, bfrag, acc1, 0, 0, 0);
        }
    }

    __syncthreads();
    // C/D layout: col = lane&15, row = (lane>>4)*4 + reg
#pragma unroll
    for (int r = 0; r < 4; ++r) {
        const int brow = mh * 32 + (lane >> 4) * 4 + r;
        const int col  = cq * 16 + (lane & 15);
        Csm[brow * 65 + col]        = acc0[r];
        Csm[(brow + 16) * 65 + col] = acc1[r];
    }
    __syncthreads();

    // fused pointwise LSTM cell
    const int hl = tid & 15;
    const int hg = h0 + hl;
    const float bi = bias[hg];
    const float bf = bias[512 + hg];
    const float bg = bias[1024 + hg];
    const float bo = bias[1536 + hg];
#pragma unroll
    for (int i = 0; i < 2; ++i) {
        const int b = (tid >> 4) * 2 + i;
        const float gi = Csm[b * 65 + hl]      + bi;
        const float gf = Csm[b * 65 + 16 + hl] + bf;
        const float gg = Csm[b * 65 + 32 + hl] + bg;
        const float go = Csm[b * 65 + 48 + hl] + bo;
        const float cprev = (t > 0) ? c_st[b * NC_ + hg] : 0.f;
        const float si = 1.f / (1.f + __expf(-gi));
        const float sf = 1.f / (1.f + __expf(-gf));
        const float so = 1.f / (1.f + __expf(-go));
        const float tg = 2.f / (1.f + __expf(-2.f * gg)) - 1.f;   // tanh
        const float cn = sf * cprev + si * tg;
        const float th = 2.f / (1.f + __expf(-2.f * cn)) - 1.f;   // tanh
        const float hn = so * th;
        c_st[b * NC_ + hg] = cn;
        // reference reshape is a flat reinterpret: out[b][t*512 + n]
        out[(size_t)b * (T_ * NC_) + (size_t)t * NC_ + hg] = hn;
        ring[((size_t)(t & 63) * B_ + b) * NC_ + hg] = (_Float16)hn;
    }
}

extern "C" void kernel_launch(void* const* d_in, const int* in_sizes, int n_in,
                              void* d_out, int out_size, void* d_ws, size_t ws_size,
                              hipStream_t stream) {
    const float* x   = (const float*)d_in[0];
    const float* Wih = (const float*)d_in[1];
    const float* Whh = (const float*)d_in[2];
    const float* bih = (const float*)d_in[3];
    const float* bhh = (const float*)d_in[4];
    float* out = (float*)d_out;

    char* ws = (char*)d_ws;
    _Float16* W16  = (_Float16*)ws;
    float*    bias = (float*)(ws + OFF_BIAS);
    float*    c_st = (float*)(ws + OFF_C);
    _Float16* ring = (_Float16*)(ws + OFF_RING);

    hipLaunchKernelGGL(prep_kernel, dim3(G4), dim3(256), 0, stream,
                       Wih, Whh, bih, bhh, W16, bias);
    for (int t = 0; t < T_; ++t) {
        hipLaunchKernelGGL(lstm_step, dim3(32), dim3(512), 0, stream,
                           t, x, W16, bias, c_st, ring, out);
    }
}

// Round 3
// 10052.936 us; speedup vs baseline: 1.2819x; 1.2819x over previous
//
#include <hip/hip_runtime.h>
#include <hip/hip_fp16.h>

// Persistent 2D-LSTM. B=64, NC=512, T=1024, P=8, F=192, K_total=1216.
// 64 WGs x 512 thr; weights fp16 in VGPRs (loaded once); per-step cross-WG
// sync via agent-scope atomics on done[] counters; h exchanged through a
// 64-slot fp16 ring stored in MFMA A-fragment layout.
// Ring half-layout: slot*32768 + (kcl*4 + ksub)*512 + b*8 + pc
//   where channel ch = kcl*32 + ksub*8 + pc.

typedef __attribute__((ext_vector_type(8))) _Float16 half8;
typedef __attribute__((ext_vector_type(4))) float f32x4;

#define T_    1024
#define NWG   64

// ws layout: done[1024*8] u32 at 0 (32 KB), ring at 32768 (64*512*64*2 = 4 MB)
#define OFF_RING 32768

__global__ __launch_bounds__(512, 2) void lstm_persist(
    const float* __restrict__ x, const float* __restrict__ Wih,
    const float* __restrict__ Whh, const float* __restrict__ bih,
    const float* __restrict__ bhh, float* __restrict__ out,
    _Float16* ring, unsigned* done)
{
    __shared__ float Psm[4][64][33];   // K-group partials
    __shared__ float cst[512];         // c-state: [b][ch_local]

    const int tid = threadIdx.x;
    const int l   = tid & 63;
    const int wv  = tid >> 6;     // wave 0..7
    const int ks  = wv & 3;       // K-group: chunks c with c%4==ks
    const int mh  = wv >> 2;      // batch half 0..1
    const int w   = blockIdx.x;   // 0..63: owns channels w*8..w*8+7 (all 4 gates)
    const int l15 = l & 15, l4 = l >> 4;

    // ---- load weight fragments (once) ----
    // col c (0..31) -> gate row rj = (c&3)*512 + w*8 + (c>>2)
    half8 Bfr[2][10];
#pragma unroll
    for (int c = 0; c < 38; ++c) {
        if ((c & 3) != ks) continue;
#pragma unroll
        for (int nb = 0; nb < 2; ++nb) {
            const int col = nb * 16 + l15;
            const int rj  = (col & 3) * 512 + w * 8 + (col >> 2);
            const float* src = (c < 22)
                ? (Wih + (size_t)rj * 704 + c * 32 + l4 * 8)
                : (Whh + (size_t)rj * 512 + (c - 22) * 32 + l4 * 8);
            float4 v0 = ((const float4*)src)[0];
            float4 v1 = ((const float4*)src)[1];
            half8 hb;
            hb[0] = (_Float16)v0.x; hb[1] = (_Float16)v0.y;
            hb[2] = (_Float16)v0.z; hb[3] = (_Float16)v0.w;
            hb[4] = (_Float16)v1.x; hb[5] = (_Float16)v1.y;
            hb[6] = (_Float16)v1.z; hb[7] = (_Float16)v1.w;
            Bfr[nb][c >> 2] = hb;
        }
    }

    // ---- pointwise role: thread -> (batch pb, local channel pc) ----
    const int pb = tid >> 3, pc = tid & 7;
    const int gc = w * 8 + pc;                  // global channel
    const float bI = bih[gc]        + bhh[gc];
    const float bF = bih[512 + gc]  + bhh[512 + gc];
    const float bG = bih[1024 + gc] + bhh[1024 + gc];
    const float bO = bih[1536 + gc] + bhh[1536 + gc];
    cst[tid] = 0.f;

    const half8* rp = (const half8*)ring;
    // producer half8-index base: (kcl*4 + ksub)*64 with kcl = w>>2, ksub = w&3
    const unsigned prod_base = ((unsigned)(w >> 2) * 4 + (unsigned)(w & 3)) * 64u;

    for (int t = 0; t < T_; ++t) {
        f32x4 acc[2][2];
#pragma unroll
        for (int ii = 0; ii < 2; ++ii)
#pragma unroll
            for (int nb = 0; nb < 2; ++nb)
                acc[ii][nb] = (f32x4){0.f, 0.f, 0.f, 0.f};

        const int y = t >> 5, xc = t & 31;

        // ---- pass 1a: x chunks (c = 0..5), fp32->fp16 on the fly ----
#pragma unroll
        for (int c = 0; c < 6; ++c) {
            if ((c & 3) != ks) continue;
#pragma unroll
            for (int ii = 0; ii < 2; ++ii) {
                const int b  = (mh * 2 + ii) * 16 + l15;
                const int k0 = c * 32 + l4 * 8;
                const float* xs = x + ((size_t)(b * 3 + (k0 >> 6)) * 256
                                       + y * 8 + ((k0 >> 3) & 7)) * 256 + xc * 8;
                float4 v0 = ((const float4*)xs)[0];
                float4 v1 = ((const float4*)xs)[1];
                half8 a;
                a[0] = (_Float16)v0.x; a[1] = (_Float16)v0.y;
                a[2] = (_Float16)v0.z; a[3] = (_Float16)v0.w;
                a[4] = (_Float16)v1.x; a[5] = (_Float16)v1.y;
                a[6] = (_Float16)v1.z; a[7] = (_Float16)v1.w;
                acc[ii][0] = __builtin_amdgcn_mfma_f32_16x16x32_f16(a, Bfr[0][c >> 2], acc[ii][0], 0, 0, 0);
                acc[ii][1] = __builtin_amdgcn_mfma_f32_16x16x32_f16(a, Bfr[1][c >> 2], acc[ii][1], 0, 0, 0);
            }
        }
        // ---- pass 1b: h(t-32) chunks (c = 6..21) ----
        if (t >= 32) {
            const int sO = (t - 32) & 63;
#pragma unroll
            for (int c = 6; c < 22; ++c) {
                if ((c & 3) != ks) continue;
#pragma unroll
                for (int ii = 0; ii < 2; ++ii) {
                    const int b = (mh * 2 + ii) * 16 + l15;
                    half8 a = rp[((size_t)sO * 4096 + (size_t)((c - 6) * 4 + l4) * 64) + b];
                    acc[ii][0] = __builtin_amdgcn_mfma_f32_16x16x32_f16(a, Bfr[0][c >> 2], acc[ii][0], 0, 0, 0);
                    acc[ii][1] = __builtin_amdgcn_mfma_f32_16x16x32_f16(a, Bfr[1][c >> 2], acc[ii][1], 0, 0, 0);
                }
            }
        }

        // ---- wait for all WGs to have published h(t-1) ----
        if (t > 0) {
            if (tid == 0) {
                unsigned* dp = done + (size_t)(t - 1) * 8;
                unsigned s;
                do {
                    s = 0;
#pragma unroll
                    for (int i = 0; i < 8; ++i)
                        s += __hip_atomic_load(dp + i, __ATOMIC_RELAXED, __HIP_MEMORY_SCOPE_AGENT);
                    if (s < NWG) __builtin_amdgcn_s_sleep(2);
                } while (s < NWG);
            }
        }
        __syncthreads();
        // ---- pass 2: h(t-1) chunks (c = 22..37) ----
        if (t > 0) {
            __builtin_amdgcn_fence(__ATOMIC_ACQUIRE, "agent");
            const int sP = (t - 1) & 63;
#pragma unroll
            for (int c = 22; c < 38; ++c) {
                if ((c & 3) != ks) continue;
#pragma unroll
                for (int ii = 0; ii < 2; ++ii) {
                    const int b = (mh * 2 + ii) * 16 + l15;
                    half8 a = rp[((size_t)sP * 4096 + (size_t)((c - 22) * 4 + l4) * 64) + b];
                    acc[ii][0] = __builtin_amdgcn_mfma_f32_16x16x32_f16(a, Bfr[0][c >> 2], acc[ii][0], 0, 0, 0);
                    acc[ii][1] = __builtin_amdgcn_mfma_f32_16x16x32_f16(a, Bfr[1][c >> 2], acc[ii][1], 0, 0, 0);
                }
            }
        }

        // ---- K-group partials -> LDS ----
#pragma unroll
        for (int ii = 0; ii < 2; ++ii)
#pragma unroll
            for (int nb = 0; nb < 2; ++nb)
#pragma unroll
                for (int r = 0; r < 4; ++r)
                    Psm[ks][(mh * 2 + ii) * 16 + l4 * 4 + r][nb * 16 + l15] = acc[ii][nb][r];
        __syncthreads();

        // ---- fused LSTM pointwise: thread (pb, pc) ----
        float gi = bI, gf = bF, gg = bG, go = bO;
#pragma unroll
        for (int k4 = 0; k4 < 4; ++k4) {
            gi += Psm[k4][pb][pc * 4 + 0];
            gf += Psm[k4][pb][pc * 4 + 1];
            gg += Psm[k4][pb][pc * 4 + 2];
            go += Psm[k4][pb][pc * 4 + 3];
        }
        const float cprev = cst[tid];
        const float si = 1.f / (1.f + __expf(-gi));
        const float sf = 1.f / (1.f + __expf(-gf));
        const float so = 1.f / (1.f + __expf(-go));
        const float tg = 2.f / (1.f + __expf(-2.f * gg)) - 1.f;
        const float cn = sf * cprev + si * tg;
        const float th = 2.f / (1.f + __expf(-2.f * cn)) - 1.f;
        const float hn = so * th;
        cst[tid] = cn;
        out[(size_t)pb * (T_ * 512) + (size_t)t * 512 + gc] = hn;

        // ---- publish h to ring (fragment layout), u32 pairs, agent scope ----
        const float hnb = __shfl_xor(hn, 1);
        if ((pc & 1) == 0) {
            union { _Float16 q[2]; unsigned u; } pk;
            pk.q[0] = (_Float16)hn;
            pk.q[1] = (_Float16)hnb;
            // half index = (slot*4096 + prod_base + pb)*8 + pc
            const unsigned hidx = ((unsigned)(t & 63) * 4096u + prod_base + (unsigned)pb) * 8u + (unsigned)pc;
            __hip_atomic_store((unsigned*)(ring + hidx), pk.u,
                               __ATOMIC_RELAXED, __HIP_MEMORY_SCOPE_AGENT);
        }
        __builtin_amdgcn_s_waitcnt(0);   // all own stores at coherence point
        __syncthreads();
        if (tid == 0)
            __hip_atomic_fetch_add(&done[(size_t)t * 8 + (w & 7)], 1u,
                                   __ATOMIC_RELEASE, __HIP_MEMORY_SCOPE_AGENT);
    }
}

extern "C" void kernel_launch(void* const* d_in, const int* in_sizes, int n_in,
                              void* d_out, int out_size, void* d_ws, size_t ws_size,
                              hipStream_t stream) {
    const float* x   = (const float*)d_in[0];
    const float* Wih = (const float*)d_in[1];
    const float* Whh = (const float*)d_in[2];
    const float* bih = (const float*)d_in[3];
    const float* bhh = (const float*)d_in[4];
    float* out = (float*)d_out;

    char* ws = (char*)d_ws;
    unsigned*  done = (unsigned*)ws;
    _Float16*  ring = (_Float16*)(ws + OFF_RING);

    hipMemsetAsync(done, 0, T_ * 8 * sizeof(unsigned), stream);
    hipLaunchKernelGGL(lstm_persist, dim3(NWG), dim3(512), 0, stream,
                       x, Wih, Whh, bih, bhh, out, ring, done);
}